// Round 1
// baseline (2447.176 us; speedup 1.0000x reference)
//
#include <hip/hip_runtime.h>

// Problem constants (fixed by reference)
#define Bn 32
#define Cc 512
#define CI 256
#define Nn 3136          // 56*56
#define EPSbn 1e-5f

constexpr int BM = 64, BN = 64, BK = 16;

// Generic tiled GEMM over channel dim:
//   acc[m,n] = sum_k A[b?][m,k] * X[b][k,n]
// EPI 0: out[b][m,n] = acc + bias[m]            (bias may be null)
// EPI 2: z = acc + bias[m] + resid[b][m,n];  atomicAdd per-channel sum/sumsq
// EPI 3: z = acc + bias[m] + resid[b][m,n];  out = (z-mean[m])*rstd[m]*gamma[m]+beta[m]
template <int EPI>
__global__ __launch_bounds__(256) void gemm_wx(
    const float* __restrict__ A, long a_bs,
    const float* __restrict__ X, long x_bs,
    const float* __restrict__ bias,
    const float* __restrict__ resid, long r_bs,
    float* __restrict__ out, long o_bs,
    int M, int N, int K,
    float* __restrict__ stats,          // [2*Cc] (sum, sumsq)
    const float* __restrict__ mstd,     // [2*Cc] (mean, rstd)
    const float* __restrict__ gamma,
    const float* __restrict__ beta)
{
    __shared__ float As[BK][BM];
    __shared__ float Bs[BK][BN];

    const int b  = blockIdx.z;
    const int m0 = blockIdx.y * BM;
    const int n0 = blockIdx.x * BN;
    const float* Ab = A + (long)b * a_bs;
    const float* Xb = X + (long)b * x_bs;

    const int tid = threadIdx.x;
    const int tx = tid & 15, ty = tid >> 4;
    // A-tile loader: 64 rows x 16 k, float4 per thread
    const int ra  = tid >> 2;
    const int ca4 = (tid & 3) << 2;
    // B-tile loader: 16 k x 64 n, float4 per thread
    const int rb  = tid >> 4;
    const int cb4 = (tid & 15) << 2;

    float acc[4][4] = {};

    for (int k0 = 0; k0 < K; k0 += BK) {
        const float4 av = *(const float4*)&Ab[(long)(m0 + ra) * K + k0 + ca4];
        const float4 bv = *(const float4*)&Xb[(long)(k0 + rb) * N + n0 + cb4];
        __syncthreads();   // previous iter's reads done before overwrite
        As[ca4 + 0][ra] = av.x;
        As[ca4 + 1][ra] = av.y;
        As[ca4 + 2][ra] = av.z;
        As[ca4 + 3][ra] = av.w;
        *(float4*)&Bs[rb][cb4] = bv;
        __syncthreads();
#pragma unroll
        for (int k = 0; k < BK; ++k) {
            const float4 a4 = *(const float4*)&As[k][ty * 4];
            const float4 b4 = *(const float4*)&Bs[k][tx * 4];
            const float ar[4] = {a4.x, a4.y, a4.z, a4.w};
            const float br[4] = {b4.x, b4.y, b4.z, b4.w};
#pragma unroll
            for (int i = 0; i < 4; ++i)
#pragma unroll
                for (int j = 0; j < 4; ++j)
                    acc[i][j] += ar[i] * br[j];
        }
    }

    if constexpr (EPI == 0) {
#pragma unroll
        for (int i = 0; i < 4; ++i) {
            const int row = m0 + ty * 4 + i;
            const float bvl = bias ? bias[row] : 0.0f;
            float4 o;
            o.x = acc[i][0] + bvl; o.y = acc[i][1] + bvl;
            o.z = acc[i][2] + bvl; o.w = acc[i][3] + bvl;
            *(float4*)&out[(long)b * o_bs + (long)row * N + n0 + tx * 4] = o;
        }
    } else if constexpr (EPI == 2) {
        __shared__ float redS[BM][17];
        __shared__ float redQ[BM][17];
#pragma unroll
        for (int i = 0; i < 4; ++i) {
            const int r = ty * 4 + i;
            const int row = m0 + r;
            const float bvl = bias[row];
            const float4 xr = *(const float4*)&resid[(long)b * r_bs + (long)row * N + n0 + tx * 4];
            const float z0 = acc[i][0] + bvl + xr.x;
            const float z1 = acc[i][1] + bvl + xr.y;
            const float z2 = acc[i][2] + bvl + xr.z;
            const float z3 = acc[i][3] + bvl + xr.w;
            redS[r][tx] = z0 + z1 + z2 + z3;
            redQ[r][tx] = z0 * z0 + z1 * z1 + z2 * z2 + z3 * z3;
        }
        __syncthreads();
        if (tid < 64) {
            float s = 0.0f, q = 0.0f;
#pragma unroll
            for (int t = 0; t < 16; ++t) { s += redS[tid][t]; q += redQ[tid][t]; }
            atomicAdd(&stats[m0 + tid], s);
            atomicAdd(&stats[Cc + m0 + tid], q);
        }
    } else {  // EPI == 3
#pragma unroll
        for (int i = 0; i < 4; ++i) {
            const int row = m0 + ty * 4 + i;
            const float bvl = bias[row];
            const float mean = mstd[row];
            const float rstd = mstd[Cc + row];
            const float gm = gamma[row];
            const float bt = beta[row];
            const float4 xr = *(const float4*)&resid[(long)b * r_bs + (long)row * N + n0 + tx * 4];
            float4 o;
            o.x = (acc[i][0] + bvl + xr.x - mean) * rstd * gm + bt;
            o.y = (acc[i][1] + bvl + xr.y - mean) * rstd * gm + bt;
            o.z = (acc[i][2] + bvl + xr.z - mean) * rstd * gm + bt;
            o.w = (acc[i][3] + bvl + xr.w - mean) * rstd * gm + bt;
            *(float4*)&out[(long)b * o_bs + (long)row * N + n0 + tx * 4] = o;
        }
    }
}

// F[b][c][d] = (1/Nn) * sum_n T[b][c][n] * P[b][d][n]   (A @ B^T, both row-major [CI, Nn])
__global__ __launch_bounds__(256) void gram_kernel(
    const float* __restrict__ T, const float* __restrict__ P, float* __restrict__ F)
{
    __shared__ float As[BK][BM];
    __shared__ float Bs[BK][BN];

    const int b  = blockIdx.z;
    const int m0 = blockIdx.y * BM;  // c
    const int n0 = blockIdx.x * BN;  // d
    const float* Tb = T + (long)b * CI * Nn;
    const float* Pb = P + (long)b * CI * Nn;

    const int tid = threadIdx.x;
    const int tx = tid & 15, ty = tid >> 4;
    const int ra  = tid >> 2;
    const int ca4 = (tid & 3) << 2;

    float acc[4][4] = {};

    for (int k0 = 0; k0 < Nn; k0 += BK) {
        const float4 av = *(const float4*)&Tb[(long)(m0 + ra) * Nn + k0 + ca4];
        const float4 bv = *(const float4*)&Pb[(long)(n0 + ra) * Nn + k0 + ca4];
        __syncthreads();
        As[ca4 + 0][ra] = av.x;
        As[ca4 + 1][ra] = av.y;
        As[ca4 + 2][ra] = av.z;
        As[ca4 + 3][ra] = av.w;
        Bs[ca4 + 0][ra] = bv.x;
        Bs[ca4 + 1][ra] = bv.y;
        Bs[ca4 + 2][ra] = bv.z;
        Bs[ca4 + 3][ra] = bv.w;
        __syncthreads();
#pragma unroll
        for (int k = 0; k < BK; ++k) {
            const float4 a4 = *(const float4*)&As[k][ty * 4];
            const float4 b4 = *(const float4*)&Bs[k][tx * 4];
            const float ar[4] = {a4.x, a4.y, a4.z, a4.w};
            const float br[4] = {b4.x, b4.y, b4.z, b4.w};
#pragma unroll
            for (int i = 0; i < 4; ++i)
#pragma unroll
                for (int j = 0; j < 4; ++j)
                    acc[i][j] += ar[i] * br[j];
        }
    }

    const float scale = 1.0f / (float)Nn;
#pragma unroll
    for (int i = 0; i < 4; ++i) {
        const int row = m0 + ty * 4 + i;
        float4 o;
        o.x = acc[i][0] * scale; o.y = acc[i][1] * scale;
        o.z = acc[i][2] * scale; o.w = acc[i][3] * scale;
        *(float4*)&F[(long)b * CI * CI + (long)row * CI + n0 + tx * 4] = o;
    }
}

__global__ void finalize_stats(const float* __restrict__ stats, float* __restrict__ mstd)
{
    const int c = threadIdx.x;  // 512
    const float inv = 1.0f / (float)(Bn * Nn);
    const float mean = stats[c] * inv;
    const float var  = stats[Cc + c] * inv - mean * mean;
    mstd[c] = mean;
    mstd[Cc + c] = rsqrtf(var + EPSbn);
}

extern "C" void kernel_launch(void* const* d_in, const int* in_sizes, int n_in,
                              void* d_out, int out_size, void* d_ws, size_t ws_size,
                              hipStream_t stream)
{
    const float* x     = (const float*)d_in[0];
    const float* g_w   = (const float*)d_in[1];
    const float* g_b   = (const float*)d_in[2];
    const float* th_w  = (const float*)d_in[3];
    const float* th_b  = (const float*)d_in[4];
    const float* ph_w  = (const float*)d_in[5];
    const float* ph_b  = (const float*)d_in[6];
    const float* W_w   = (const float*)d_in[7];
    const float* W_b   = (const float*)d_in[8];
    const float* gamma = (const float*)d_in[9];
    const float* beta  = (const float*)d_in[10];
    float* out = (float*)d_out;

    // Workspace layout (all float): T, P: [B, CI, Nn]; F: [B, CI, CI]; stats/mstd: [2*Cc]
    float* T     = (float*)d_ws;
    float* P     = T + (size_t)Bn * CI * Nn;
    float* F     = P + (size_t)Bn * CI * Nn;
    float* stats = F + (size_t)Bn * CI * CI;
    float* mstd  = stats + 2 * Cc;

    hipMemsetAsync(stats, 0, 2 * Cc * sizeof(float), stream);

    const dim3 blk(256);
    const dim3 gConv(Nn / BN, CI / BM, Bn);   // 49 x 4 x 32
    const dim3 gGram(CI / BN, CI / BM, Bn);   //  4 x 4 x 32
    const dim3 gZ(Nn / BN, Cc / BM, Bn);      // 49 x 8 x 32

    const long xbs = (long)Cc * Nn;   // x batch stride
    const long ibs = (long)CI * Nn;   // intermediate batch stride

    // theta -> T
    gemm_wx<0><<<gConv, blk, 0, stream>>>(th_w, 0, x, xbs, th_b, nullptr, 0,
                                          T, ibs, CI, Nn, Cc,
                                          nullptr, nullptr, nullptr, nullptr);
    // phi -> P
    gemm_wx<0><<<gConv, blk, 0, stream>>>(ph_w, 0, x, xbs, ph_b, nullptr, 0,
                                          P, ibs, CI, Nn, Cc,
                                          nullptr, nullptr, nullptr, nullptr);
    // f = theta @ phi^T / N -> F
    gram_kernel<<<gGram, blk, 0, stream>>>(T, P, F);
    // g -> T (theta no longer needed)
    gemm_wx<0><<<gConv, blk, 0, stream>>>(g_w, 0, x, xbs, g_b, nullptr, 0,
                                          T, ibs, CI, Nn, Cc,
                                          nullptr, nullptr, nullptr, nullptr);
    // y = f @ g -> P (phi no longer needed); per-batch A matrix
    gemm_wx<0><<<gConv, blk, 0, stream>>>(F, (long)CI * CI, T, ibs, nullptr, nullptr, 0,
                                          P, ibs, CI, Nn, CI,
                                          nullptr, nullptr, nullptr, nullptr);
    // z = W_w @ y + W_b + x : accumulate BN stats (z not materialized)
    gemm_wx<2><<<gZ, blk, 0, stream>>>(W_w, 0, P, ibs, W_b, x, xbs,
                                       nullptr, 0, Cc, Nn, CI,
                                       stats, nullptr, nullptr, nullptr);
    finalize_stats<<<1, Cc, 0, stream>>>(stats, mstd);
    // recompute z, normalize, write out
    gemm_wx<3><<<gZ, blk, 0, stream>>>(W_w, 0, P, ibs, W_b, x, xbs,
                                       out, xbs, Cc, Nn, CI,
                                       nullptr, mstd, gamma, beta);
}

// Round 2
// 878.710 us; speedup vs baseline: 2.7850x; 2.7850x over previous
//
#include <hip/hip_runtime.h>

// Problem constants
#define Bn   32
#define Cc   512
#define CIc  256
#define Nsp  3136      // 56*56
#define Npad 3200      // spatial padded to multiple of 128 (tile coverage)
#define EPSbn 1e-5f

typedef __attribute__((ext_vector_type(8))) short v8s;   // 8 x bf16 (4 VGPRs)
typedef __attribute__((ext_vector_type(4))) float v4f;   // MFMA accumulator

__device__ __forceinline__ unsigned short f2bf(float f) {
    unsigned int u = __builtin_bit_cast(unsigned int, f);
    u += 0x7fffu + ((u >> 16) & 1u);          // RNE
    return (unsigned short)(u >> 16);
}

// async global->LDS, 16B per lane; LDS dest = wave-uniform base + lane*16
__device__ __forceinline__ void async16(const unsigned short* g, unsigned short* l) {
    __builtin_amdgcn_global_load_lds(
        (const __attribute__((address_space(1))) unsigned int*)g,
        (__attribute__((address_space(3))) unsigned int*)l, 16, 0, 0);
}

// Canonical bf16 MFMA GEMM:  O[gn][gm] = sum_k A[gm][k] * B[gn][k]
// A: [M][lda] bf16 (k-contig), B: [N][ldb] bf16 (k-contig).
// Block tile 128x128 (M x N), BK=32, 4 waves in 2x2, 4x4 16x16x32 MFMAs/wave.
// EPI 0: bf16 store O[gn][gm] (+ optional biasN[gn] / biasM[gm], * scale)
// EPI 2: z = acc + biasN[gc] + x[b][gc][gsp]; per-channel sum/sumsq atomics (gsp<Nsp)
// EPI 3: out[b][gc][gsp] = (z-mean)*rstd*gamma+beta, fp32, masked gsp<Nsp
template <int EPI>
__global__ __launch_bounds__(256)
void mfma_gemm(const unsigned short* __restrict__ A, int lda, long a_bs,
               const unsigned short* __restrict__ B, int ldb, long b_bs,
               void* __restrict__ Out, int ldo, long o_bs,
               int K, float scale,
               const float* __restrict__ biasN, const float* __restrict__ biasM,
               const float* __restrict__ xres,
               float* __restrict__ stats, const float* __restrict__ mstd,
               const float* __restrict__ gamma, const float* __restrict__ beta)
{
    __shared__ __align__(16) unsigned short As[128 * 32];  // [m][k] 8KB
    __shared__ __align__(16) unsigned short Bs[128 * 32];  // [n][k] 8KB

    const int tid  = threadIdx.x;
    const int w    = tid >> 6;
    const int lane = tid & 63;
    const int b    = blockIdx.z;
    const int m0   = blockIdx.x * 128;
    const int n0   = blockIdx.y * 128;

    const unsigned short* Ab = A + (long)b * a_bs;
    const unsigned short* Bb = B + (long)b * b_bs;

    // staging map: chunk c = 2w+q covers LDS elems [c*512,(c+1)*512), lane elem = c*512+lane*8
    const int ldrow = 32 * w + (lane >> 2);
    const int ldk   = (lane & 3) * 8;
    unsigned short* lA0 = &As[(2 * w + 0) * 512];
    unsigned short* lA1 = &As[(2 * w + 1) * 512];
    unsigned short* lB0 = &Bs[(2 * w + 0) * 512];
    unsigned short* lB1 = &Bs[(2 * w + 1) * 512];
    const size_t aoff0 = (size_t)(m0 + ldrow) * lda + ldk;
    const size_t aoff1 = aoff0 + (size_t)16 * lda;
    const size_t boff0 = (size_t)(n0 + ldrow) * ldb + ldk;
    const size_t boff1 = boff0 + (size_t)16 * ldb;

    const int wm = (w & 1) * 64;       // wave tile M offset
    const int wn = (w >> 1) * 64;      // wave tile N offset
    const int fr = lane & 15;
    const int fk = (lane >> 4) * 8;

    v4f acc[4][4] = {};

    for (int k0 = 0; k0 < K; k0 += 32) {
        __syncthreads();                        // previous tile's ds_reads done
        async16(Ab + aoff0 + k0, lA0);
        async16(Ab + aoff1 + k0, lA1);
        async16(Bb + boff0 + k0, lB0);
        async16(Bb + boff1 + k0, lB1);
        __syncthreads();                        // drains vmcnt -> LDS valid

        v8s af[4], bf[4];
#pragma unroll
        for (int i = 0; i < 4; ++i)
            af[i] = *(const v8s*)&As[(wm + i * 16 + fr) * 32 + fk];
#pragma unroll
        for (int j = 0; j < 4; ++j)
            bf[j] = *(const v8s*)&Bs[(wn + j * 16 + fr) * 32 + fk];
#pragma unroll
        for (int i = 0; i < 4; ++i)
#pragma unroll
            for (int j = 0; j < 4; ++j)
                acc[i][j] = __builtin_amdgcn_mfma_f32_16x16x32_bf16(af[i], bf[j], acc[i][j], 0, 0, 0);
    }

    // C/D layout: col(n-role)=lane&15, row(m-role)=quad*4+reg -> 4 consecutive m per lane
    const int em = wm + ((lane >> 4) << 2);
    const int en = wn + fr;

    if constexpr (EPI == 0) {
        unsigned short* O = (unsigned short*)Out;
#pragma unroll
        for (int j = 0; j < 4; ++j) {
            const int gn = n0 + en + j * 16;
            const float bN = biasN ? biasN[gn] : 0.0f;
            unsigned short* orow = O + (long)b * o_bs + (size_t)gn * ldo + m0 + em;
#pragma unroll
            for (int i = 0; i < 4; ++i) {
                float4 bm = make_float4(0.f, 0.f, 0.f, 0.f);
                if (biasM) bm = *(const float4*)&biasM[m0 + em + i * 16];
                ushort4 o4;
                o4.x = f2bf(acc[i][j].x * scale + bN + bm.x);
                o4.y = f2bf(acc[i][j].y * scale + bN + bm.y);
                o4.z = f2bf(acc[i][j].z * scale + bN + bm.z);
                o4.w = f2bf(acc[i][j].w * scale + bN + bm.w);
                *(ushort4*)&orow[i * 16] = o4;
            }
        }
    } else if constexpr (EPI == 2) {
        float sj[4] = {0.f, 0.f, 0.f, 0.f}, qj[4] = {0.f, 0.f, 0.f, 0.f};
#pragma unroll
        for (int j = 0; j < 4; ++j) {
            const int gc = n0 + en + j * 16;
            const float wb = biasN[gc];
            const float* xrow = xres + (size_t)b * Cc * Nsp + (size_t)gc * Nsp;
#pragma unroll
            for (int i = 0; i < 4; ++i) {
                const int gsp = m0 + em + i * 16;
                if (gsp < Nsp) {
                    const float4 xr = *(const float4*)&xrow[gsp];
                    const float z0 = acc[i][j].x + wb + xr.x;
                    const float z1 = acc[i][j].y + wb + xr.y;
                    const float z2 = acc[i][j].z + wb + xr.z;
                    const float z3 = acc[i][j].w + wb + xr.w;
                    sj[j] += z0 + z1 + z2 + z3;
                    qj[j] += z0 * z0 + z1 * z1 + z2 * z2 + z3 * z3;
                }
            }
        }
        __syncthreads();                       // done reading As -> reuse as scratch
        float* red = (float*)As;               // [128][8] sums + [128][8] sumsq
        const int cid = (lane >> 4) + ((w & 1) << 2);
#pragma unroll
        for (int j = 0; j < 4; ++j) {
            const int cc = wn + fr + j * 16;
            red[cc * 8 + cid] = sj[j];
            red[1024 + cc * 8 + cid] = qj[j];
        }
        __syncthreads();
        if (tid < 128) {
            float s = 0.f, q = 0.f;
#pragma unroll
            for (int t = 0; t < 8; ++t) { s += red[tid * 8 + t]; q += red[1024 + tid * 8 + t]; }
            atomicAdd(&stats[n0 + tid], s);
            atomicAdd(&stats[Cc + n0 + tid], q);
        }
    } else {  // EPI == 3
        float* O = (float*)Out;
#pragma unroll
        for (int j = 0; j < 4; ++j) {
            const int gc = n0 + en + j * 16;
            const float a1 = mstd[Cc + gc] * gamma[gc];
            const float a0 = beta[gc] - mstd[gc] * a1 + biasN[gc] * a1;
            const float* xrow = xres + (size_t)b * Cc * Nsp + (size_t)gc * Nsp;
            float* orow = O + (long)b * o_bs + (size_t)gc * (size_t)ldo;
#pragma unroll
            for (int i = 0; i < 4; ++i) {
                const int gsp = m0 + em + i * 16;
                if (gsp < Nsp) {
                    const float4 xr = *(const float4*)&xrow[gsp];
                    float4 o;
                    o.x = (acc[i][j].x + xr.x) * a1 + a0;
                    o.y = (acc[i][j].y + xr.y) * a1 + a0;
                    o.z = (acc[i][j].z + xr.z) * a1 + a0;
                    o.w = (acc[i][j].w + xr.w) * a1 + a0;
                    *(float4*)&orow[gsp] = o;
                }
            }
        }
    }
}

// x fp32 [b][c][n] -> xT bf16 [b][n][c] (n rows = 3136, unpadded; OOB reads tolerated downstream)
__global__ __launch_bounds__(256)
void cast_transpose(const float* __restrict__ x, unsigned short* __restrict__ xT)
{
    __shared__ float tile[64][65];
    const int b  = blockIdx.z;
    const int n0 = blockIdx.x * 64;
    const int c0 = blockIdx.y * 64;
    const float* xb = x + (size_t)b * Cc * Nsp;
    const int t = threadIdx.x;
    const int tr  = t >> 4;            // 0..15
    const int tc4 = (t & 15) * 4;
#pragma unroll
    for (int i = 0; i < 4; ++i) {
        const int c = tr + i * 16;
        const float4 v = *(const float4*)&xb[(size_t)(c0 + c) * Nsp + n0 + tc4];
        tile[tc4 + 0][c] = v.x;
        tile[tc4 + 1][c] = v.y;
        tile[tc4 + 2][c] = v.z;
        tile[tc4 + 3][c] = v.w;
    }
    __syncthreads();
    unsigned short* xo = xT + (size_t)b * Nsp * Cc;
#pragma unroll
    for (int i = 0; i < 4; ++i) {
        const int n = tr + i * 16;
        ushort4 o;
        o.x = f2bf(tile[n][tc4 + 0]);
        o.y = f2bf(tile[n][tc4 + 1]);
        o.z = f2bf(tile[n][tc4 + 2]);
        o.w = f2bf(tile[n][tc4 + 3]);
        *(ushort4*)&xo[(size_t)(n0 + n) * Cc + c0 + tc4] = o;
    }
}

__global__ void cast_w(const float* __restrict__ src, unsigned short* __restrict__ dst, int n)
{
    const int i = (blockIdx.x * 256 + threadIdx.x) * 4;
    if (i < n) {
        const float4 v = *(const float4*)&src[i];
        ushort4 o;
        o.x = f2bf(v.x); o.y = f2bf(v.y); o.z = f2bf(v.z); o.w = f2bf(v.w);
        *(ushort4*)&dst[i] = o;
    }
}

__global__ void finalize_stats(const float* __restrict__ stats, float* __restrict__ mstd)
{
    const int c = threadIdx.x;  // 512
    const float inv = 1.0f / (float)((long)Bn * Nsp);
    const float mean = stats[c] * inv;
    const float var  = stats[Cc + c] * inv - mean * mean;
    mstd[c] = mean;
    mstd[Cc + c] = rsqrtf(var + EPSbn);
}

extern "C" void kernel_launch(void* const* d_in, const int* in_sizes, int n_in,
                              void* d_out, int out_size, void* d_ws, size_t ws_size,
                              hipStream_t stream)
{
    const float* x     = (const float*)d_in[0];
    const float* g_w   = (const float*)d_in[1];
    const float* g_b   = (const float*)d_in[2];
    const float* th_w  = (const float*)d_in[3];
    const float* th_b  = (const float*)d_in[4];
    const float* ph_w  = (const float*)d_in[5];
    const float* ph_b  = (const float*)d_in[6];
    const float* W_w   = (const float*)d_in[7];
    const float* W_b   = (const float*)d_in[8];
    const float* gamma = (const float*)d_in[9];
    const float* beta  = (const float*)d_in[10];
    float* out = (float*)d_out;

    // ws layout (bf16 elements unless noted):
    //  xT [32][3136][512]            102,760,448 B
    //  T  [32][256][3200] (theta NCHW; later reused as G [32][3200][256])   52,428,800 B
    //  P  [32][256][3200] (phi NCHW;  later reused as Y [32][3200][256])    52,428,800 B
    //  F  [32][256][256]               4,194,304 B
    //  w16: th,ph,g [256][512], W [512][256]     4 x 262,144 B
    //  stats/mstd fp32 [2*512] each
    unsigned short* xT = (unsigned short*)d_ws;
    unsigned short* T  = xT + (size_t)Bn * Nsp * Cc;
    unsigned short* P  = T + (size_t)Bn * CIc * Npad;
    unsigned short* F  = P + (size_t)Bn * CIc * Npad;
    unsigned short* w16 = F + (size_t)Bn * CIc * CIc;
    unsigned short* thw16 = w16;
    unsigned short* phw16 = w16 + 131072;
    unsigned short* gw16  = w16 + 2 * 131072;
    unsigned short* Ww16  = w16 + 3 * 131072;
    float* stats = (float*)(w16 + 4 * 131072);
    float* mstd  = stats + 2 * Cc;

    unsigned short* G = T;   // g NHWC, overwrites theta after Gram
    unsigned short* Y = P;   // y NHWC, overwrites phi after Gram

    hipMemsetAsync(stats, 0, 2 * Cc * sizeof(float), stream);

    const dim3 blk(256);
    const long xT_bs = (long)Nsp * Cc;
    const long nc_bs = (long)CIc * Npad;   // T/P ([c'][n] stride 3200)
    const long nh_bs = (long)Npad * CIc;   // G/Y ([n][c'] stride 256)

    cast_transpose<<<dim3(49, 8, Bn), blk, 0, stream>>>(x, xT);
    cast_w<<<dim3(128), blk, 0, stream>>>(th_w, thw16, 131072);
    cast_w<<<dim3(128), blk, 0, stream>>>(ph_w, phw16, 131072);
    cast_w<<<dim3(128), blk, 0, stream>>>(g_w,  gw16,  131072);
    cast_w<<<dim3(128), blk, 0, stream>>>(W_w,  Ww16,  131072);

    // theta: O[c'][n] = sum_c xT[n][c]*th_w[c'][c]   M=n(3200), N=c'(256), K=512
    mfma_gemm<0><<<dim3(25, 2, Bn), blk, 0, stream>>>(
        xT, Cc, xT_bs, thw16, Cc, 0, T, Npad, nc_bs, Cc, 1.0f,
        th_b, nullptr, nullptr, nullptr, nullptr, nullptr, nullptr);
    // phi -> P
    mfma_gemm<0><<<dim3(25, 2, Bn), blk, 0, stream>>>(
        xT, Cc, xT_bs, phw16, Cc, 0, P, Npad, nc_bs, Cc, 1.0f,
        ph_b, nullptr, nullptr, nullptr, nullptr, nullptr, nullptr);
    // Gram: F[c][d] = (1/N) sum_n phi[d][n]*theta[c][n]   M=d(256), N=c(256), K=3136
    mfma_gemm<0><<<dim3(2, 2, Bn), blk, 0, stream>>>(
        P, Npad, nc_bs, T, Npad, nc_bs, F, CIc, (long)CIc * CIc, Nsp, 1.0f / (float)Nsp,
        nullptr, nullptr, nullptr, nullptr, nullptr, nullptr, nullptr);
    // g: G[n][c'] = sum_c g_w[c'][c]*xT[n][c]   M=c'(256), N=n(3200), K=512   (overwrites T)
    mfma_gemm<0><<<dim3(2, 25, Bn), blk, 0, stream>>>(
        gw16, Cc, 0, xT, Cc, xT_bs, G, CIc, nh_bs, Cc, 1.0f,
        nullptr, g_b, nullptr, nullptr, nullptr, nullptr, nullptr);
    // y: Y[n][c'] = sum_d F[c'][d]*G[n][d]   M=c'(256), N=n(3200), K=256   (overwrites P)
    mfma_gemm<0><<<dim3(2, 25, Bn), blk, 0, stream>>>(
        F, CIc, (long)CIc * CIc, G, CIc, nh_bs, Y, CIc, nh_bs, CIc, 1.0f,
        nullptr, nullptr, nullptr, nullptr, nullptr, nullptr, nullptr);
    // z pass 1 (stats): z[n][c] = sum_c' Y[n][c']*W_w[c][c'] + W_b + x   M=n(3200), N=c(512), K=256
    mfma_gemm<2><<<dim3(25, 4, Bn), blk, 0, stream>>>(
        Y, CIc, nh_bs, Ww16, CIc, 0, nullptr, 0, 0, CIc, 1.0f,
        W_b, nullptr, x, stats, nullptr, nullptr, nullptr);
    finalize_stats<<<dim3(1), dim3(Cc), 0, stream>>>(stats, mstd);
    // z pass 2 (normalize -> out fp32 NCHW)
    mfma_gemm<3><<<dim3(25, 4, Bn), blk, 0, stream>>>(
        Y, CIc, nh_bs, Ww16, CIc, 0, out, Nsp, (long)Cc * Nsp, CIc, 1.0f,
        W_b, nullptr, x, nullptr, mstd, gamma, beta);
}